// Round 10
// baseline (303.635 us; speedup 1.0000x reference)
//
#include <hip/hip_runtime.h>
#include <hip/hip_bf16.h>

#define D_IN 128
#define D_H  256

typedef __attribute__((ext_vector_type(8))) short short8;   // 8 bf16 (4 VGPRs)
typedef __attribute__((ext_vector_type(4))) float floatx4;  // MFMA C/D frag

__device__ __forceinline__ unsigned short f2bf(float f) {
    __hip_bfloat16 h = __float2bfloat16(f);
    return *reinterpret_cast<unsigned short*>(&h);
}
__device__ __forceinline__ float bf2f(unsigned short s) {
    union { unsigned int u; float f; } v;
    v.u = ((unsigned int)s) << 16;
    return v.f;
}

// ------------- fused: histogram (+rank) AND fp32->bf16 conversions ---------
__global__ void hist_conv_k(const int* __restrict__ dst, int* __restrict__ deg,
                            int* __restrict__ rank, int E,
                            const float* __restrict__ x, unsigned short* __restrict__ xb, int nx4,
                            const float* __restrict__ w1l, unsigned short* __restrict__ w1lb,
                            const float* __restrict__ w1r, unsigned short* __restrict__ w1rb, int nw14,
                            const float* __restrict__ w2l, unsigned short* __restrict__ w2lb,
                            const float* __restrict__ w2r, unsigned short* __restrict__ w2rb, int nw24) {
    if (blockIdx.x < 512) {
        for (int e = blockIdx.x * 256 + threadIdx.x; e < E; e += 512 * 256)
            rank[e] = atomicAdd(&deg[dst[e]], 1);
        return;
    }
    int i = (blockIdx.x - 512) * 256 + threadIdx.x;
    const float* s; unsigned short* d; int k;
    if (i < nx4) { s = x; d = xb; k = i; }
    else {
        i -= nx4;
        if (i < nw14) { s = w1l; d = w1lb; k = i; }
        else {
            i -= nw14;
            if (i < nw14) { s = w1r; d = w1rb; k = i; }
            else {
                i -= nw14;
                if (i < nw24) { s = w2l; d = w2lb; k = i; }
                else {
                    i -= nw24;
                    if (i >= nw24) return;
                    s = w2r; d = w2rb; k = i;
                }
            }
        }
    }
    float4 v = ((const float4*)s)[k];
    ushort4 u;
    u.x = f2bf(v.x); u.y = f2bf(v.y); u.z = f2bf(v.z); u.w = f2bf(v.w);
    ((ushort4*)d)[k] = u;
}

__global__ __launch_bounds__(256) void scan_part_k(const int* __restrict__ deg,
                                                   int* __restrict__ bsum, int n) {
    const int b = blockIdx.x, tid = threadIdx.x;
    const int base = b * 2048;
    const int lim = min(base + 2048, n);
    int s = 0;
    for (int i = base + tid; i < lim; i += 256) s += deg[i];
    __shared__ int red[256];
    red[tid] = s; __syncthreads();
    for (int off = 128; off > 0; off >>= 1) {
        if (tid < off) red[tid] += red[tid + off];
        __syncthreads();
    }
    if (tid == 0) bsum[b] = red[0];
}

__global__ __launch_bounds__(256) void scan_final_k(const int* __restrict__ deg,
                                                    const int* __restrict__ bsum,
                                                    int* __restrict__ row_ptr,
                                                    int n, int E) {
    const int b = blockIdx.x, tid = threadIdx.x;
    const int base = b * 2048;
    __shared__ int buf[2048];
    __shared__ int ts[256];
    __shared__ int blk_prefix;
    if (tid == 0) {
        int p = 0;
        for (int i = 0; i < b; ++i) p += bsum[i];
        blk_prefix = p;
    }
    for (int i = tid; i < 2048; i += 256)
        buf[i] = (base + i < n) ? deg[base + i] : 0;
    __syncthreads();
    int local[8];
    int s = 0;
#pragma unroll
    for (int j = 0; j < 8; ++j) { local[j] = s; s += buf[tid * 8 + j]; }
    ts[tid] = s; __syncthreads();
    for (int off = 1; off < 256; off <<= 1) {
        int v = (tid >= off) ? ts[tid - off] : 0;
        __syncthreads();
        ts[tid] += v;
        __syncthreads();
    }
    const int prefix = blk_prefix + ((tid == 0) ? 0 : ts[tid - 1]);
#pragma unroll
    for (int j = 0; j < 8; ++j) {
        int idx = base + tid * 8 + j;
        if (idx < n) row_ptr[idx] = prefix + local[j];
    }
    if (b == 0 && tid == 0) row_ptr[n] = E;
}

__global__ void scatter_k(const int* __restrict__ src, const int* __restrict__ dst,
                          const int* __restrict__ rank, const int* __restrict__ row_ptr,
                          int* __restrict__ col, int E) {
    for (int e = blockIdx.x * blockDim.x + threadIdx.x; e < E; e += gridDim.x * blockDim.x)
        col[row_ptr[dst[e]] + rank[e]] = src[e];
}

// ---------------- mean aggregation v3 (R7-proven) ----------
template <int D, int UN>
__device__ __forceinline__ int agg_stage(const unsigned short* __restrict__ X,
                                         const int* __restrict__ col,
                                         int j, int e, int lane, float* acc) {
    constexpr int V = D / 64;
    for (; j + UN <= e; j += UN) {
        int cs[UN];
#pragma unroll
        for (int u = 0; u < UN; ++u) cs[u] = col[j + u];
        if constexpr (V == 2) {
            unsigned int vals[UN];
#pragma unroll
            for (int u = 0; u < UN; ++u)
                vals[u] = *(const unsigned int*)(X + (size_t)cs[u] * D + lane * 2);
#pragma unroll
            for (int u = 0; u < UN; ++u) {
                acc[0] += bf2f((unsigned short)(vals[u] & 0xffff));
                acc[1] += bf2f((unsigned short)(vals[u] >> 16));
            }
        } else {
            ushort4 vals[UN];
#pragma unroll
            for (int u = 0; u < UN; ++u)
                vals[u] = *(const ushort4*)(X + (size_t)cs[u] * D + lane * 4);
#pragma unroll
            for (int u = 0; u < UN; ++u) {
                acc[0] += bf2f(vals[u].x); acc[1] += bf2f(vals[u].y);
                acc[2] += bf2f(vals[u].z); acc[3] += bf2f(vals[u].w);
            }
        }
    }
    return j;
}

template <int D>
__global__ __launch_bounds__(256) void aggregate_v3(
    const unsigned short* __restrict__ X, const int* __restrict__ col,
    const int* __restrict__ rp, unsigned short* __restrict__ out, int Mnodes) {
    int node = __builtin_amdgcn_readfirstlane((blockIdx.x << 2) + (threadIdx.x >> 6));
    if (node >= Mnodes) return;
    const int lane = threadIdx.x & 63;
    const int s = rp[node], e = rp[node + 1];
    constexpr int V = D / 64;
    float acc[V] = {0.f};

    int j = s;
    j = agg_stage<D, 8>(X, col, j, e, lane, acc);
    j = agg_stage<D, 4>(X, col, j, e, lane, acc);
    j = agg_stage<D, 2>(X, col, j, e, lane, acc);
    j = agg_stage<D, 1>(X, col, j, e, lane, acc);

    const float inv = 1.f / fmaxf((float)(e - s), 1.f);
    if constexpr (V == 2) {
        ushort2 o;
        o.x = f2bf(acc[0] * inv); o.y = f2bf(acc[1] * inv);
        *(ushort2*)(out + (size_t)node * D + lane * 2) = o;
    } else {
        ushort4 o;
        o.x = f2bf(acc[0] * inv); o.y = f2bf(acc[1] * inv);
        o.z = f2bf(acc[2] * inv); o.w = f2bf(acc[3] * inv);
        *(ushort4*)(out + (size_t)node * D + lane * 4) = o;
    }
}

// ---------------- dual-input bf16 MFMA GEMM, 128x256, global_load_lds ------
// Staging via async global->LDS (16B/lane). LDS rows unpadded (64B); fetch-side
// XOR swizzle seg' = seg ^ ((row>>1)&3) makes b128 frag reads 2-way max.
template <int K, bool HEAD>
__global__ __launch_bounds__(256) void gemm_mfma_k(
    const unsigned short* __restrict__ A1, const unsigned short* __restrict__ W1,
    const unsigned short* __restrict__ A2, const unsigned short* __restrict__ W2,
    const float* __restrict__ bias, unsigned short* __restrict__ Hout,
    const float* __restrict__ hw, const float* __restrict__ hb,
    float* __restrict__ out, int M) {
    __shared__ __align__(16) unsigned short sA[128 * 32];   // 8 KB
    __shared__ __align__(16) unsigned short sB[256 * 32];   // 16 KB
    __shared__ float head_acc[128];

    const int tid = threadIdx.x;
    const int wave = tid >> 6;
    const int lane = tid & 63;
    const int c = lane & 15;
    const int q = lane >> 4;
    const int m0 = blockIdx.x * 128;

    if (HEAD && tid < 128) head_acc[tid] = 0.f;  // ordered by k-loop barriers

    floatx4 acc[8][4];
#pragma unroll
    for (int mi = 0; mi < 8; ++mi)
#pragma unroll
        for (int ni = 0; ni < 4; ++ni) acc[mi][ni] = (floatx4){0.f, 0.f, 0.f, 0.f};

    // staging slot maps: slot L -> row = L>>2, stored seg = L&3,
    // fetched global seg = (L&3) ^ ((row>>1)&3)
    int aRow[2], aSegU[2], gA[2];
#pragma unroll
    for (int j = 0; j < 2; ++j) {
        const int L = j * 256 + tid;
        aRow[j] = L >> 2;
        aSegU[j] = ((L & 3) ^ ((aRow[j] >> 1) & 3)) * 8;
        gA[j] = min(m0 + aRow[j], M - 1);
    }
    int bRow[4], bSegU[4];
#pragma unroll
    for (int j = 0; j < 4; ++j) {
        const int L = j * 256 + tid;
        bRow[j] = L >> 2;
        bSegU[j] = ((L & 3) ^ ((bRow[j] >> 1) & 3)) * 8;
    }
    // fragment read offsets: swizzle term depends only on c (row>>1)&3 == (c>>1)&3
    const int sc = (q ^ ((c >> 1) & 3)) * 8;

    for (int phase = 0; phase < 2; ++phase) {
        const unsigned short* Ap = phase ? A2 : A1;
        const unsigned short* Wp = phase ? W2 : W1;
        for (int k0 = 0; k0 < K; k0 += 32) {
            __syncthreads();            // prev iteration's frag reads done
#pragma unroll
            for (int j = 0; j < 2; ++j)
                __builtin_amdgcn_global_load_lds(
                    (const unsigned int*)(Ap + (size_t)gA[j] * K + k0 + aSegU[j]),
                    (unsigned int*)&sA[(j * 256 + wave * 64) * 8], 16, 0, 0);
#pragma unroll
            for (int j = 0; j < 4; ++j)
                __builtin_amdgcn_global_load_lds(
                    (const unsigned int*)(Wp + (size_t)bRow[j] * K + k0 + bSegU[j]),
                    (unsigned int*)&sB[(j * 256 + wave * 64) * 8], 16, 0, 0);
            __syncthreads();            // vmcnt drained by compiler before barrier

            short8 af[8], bf[4];
#pragma unroll
            for (int mi = 0; mi < 8; ++mi)
                af[mi] = *(const short8*)&sA[(mi * 16 + c) * 32 + sc];
#pragma unroll
            for (int ni = 0; ni < 4; ++ni)
                bf[ni] = *(const short8*)&sB[(wave * 64 + ni * 16 + c) * 32 + sc];
#pragma unroll
            for (int mi = 0; mi < 8; ++mi)
#pragma unroll
                for (int ni = 0; ni < 4; ++ni)
                    acc[mi][ni] = __builtin_amdgcn_mfma_f32_16x16x32_bf16(
                        af[mi], bf[ni], acc[mi][ni], 0, 0, 0);
        }
    }

    if (!HEAD) {
#pragma unroll
        for (int mi = 0; mi < 8; ++mi)
#pragma unroll
            for (int ni = 0; ni < 4; ++ni) {
                const int n = wave * 64 + ni * 16 + c;
                const float bv = bias[n];
#pragma unroll
                for (int reg = 0; reg < 4; ++reg) {
                    const int m = m0 + mi * 16 + q * 4 + reg;
                    if (m < M) {
                        float v = fmaxf(acc[mi][ni][reg] + bv, 0.f);
                        Hout[(size_t)m * 256 + n] = f2bf(v);
                    }
                }
            }
    } else {
#pragma unroll
        for (int mi = 0; mi < 8; ++mi) {
            float p[4] = {0.f, 0.f, 0.f, 0.f};
#pragma unroll
            for (int ni = 0; ni < 4; ++ni) {
                const int n = wave * 64 + ni * 16 + c;
                const float bv = bias[n];
                const float hv = hw[n];
#pragma unroll
                for (int reg = 0; reg < 4; ++reg)
                    p[reg] += fmaxf(acc[mi][ni][reg] + bv, 0.f) * hv;
            }
#pragma unroll
            for (int reg = 0; reg < 4; ++reg) {
                float v = p[reg];
                v += __shfl_xor(v, 1, 64);
                v += __shfl_xor(v, 2, 64);
                v += __shfl_xor(v, 4, 64);
                v += __shfl_xor(v, 8, 64);
                if (c == 0) atomicAdd(&head_acc[mi * 16 + q * 4 + reg], v);
            }
        }
        __syncthreads();
        if (tid < 128) {
            const int m = m0 + tid;
            if (m < M) out[m] = head_acc[tid] + hb[0];
        }
    }
}

// ---------------- launch ----------------
extern "C" void kernel_launch(void* const* d_in, const int* in_sizes, int n_in,
                              void* d_out, int out_size, void* d_ws, size_t ws_size,
                              hipStream_t stream) {
    const float* x    = (const float*)d_in[0];
    const int*   ei   = (const int*)d_in[1];
    const float* W1l  = (const float*)d_in[2];
    const float* b1   = (const float*)d_in[3];
    const float* W1r  = (const float*)d_in[4];
    const float* W2l  = (const float*)d_in[5];
    const float* b2   = (const float*)d_in[6];
    const float* W2r  = (const float*)d_in[7];
    const float* hw   = (const float*)d_in[8];
    const float* hb   = (const float*)d_in[9];
    float* out = (float*)d_out;

    const int M = in_sizes[0] / D_IN;       // 50000
    const int E = in_sizes[1] / 2;          // 800000
    const int* src = ei;
    const int* dst = ei + E;

    size_t off = 0;
    auto alloc = [&](size_t bytes) -> void* {
        void* p = (char*)d_ws + off;
        off += (bytes + 255) & ~(size_t)255;
        return p;
    };
    int* deg  = (int*)alloc((size_t)M * 4);
    int* rp   = (int*)alloc((size_t)(M + 1) * 4);
    int* bsum = (int*)alloc(256 * 4);
    int* rank = (int*)alloc((size_t)E * 4);
    int* col  = (int*)alloc((size_t)E * 4);
    unsigned short* xb    = (unsigned short*)alloc((size_t)M * D_IN * 2);
    unsigned short* w1lb  = (unsigned short*)alloc((size_t)D_H * D_IN * 2);
    unsigned short* w1rb  = (unsigned short*)alloc((size_t)D_H * D_IN * 2);
    unsigned short* w2lb  = (unsigned short*)alloc((size_t)D_H * D_H * 2);
    unsigned short* w2rb  = (unsigned short*)alloc((size_t)D_H * D_H * 2);
    unsigned short* mean1 = (unsigned short*)alloc((size_t)M * D_IN * 2);
    unsigned short* h1    = (unsigned short*)alloc((size_t)M * D_H * 2);
    unsigned short* mean2 = (unsigned short*)alloc((size_t)M * D_H * 2);

    hipMemsetAsync(deg, 0, (size_t)M * 4, stream);

    // fused histogram + conversions
    const int nx4 = (M * D_IN) / 4;
    const int nw14 = (D_H * D_IN) / 4;
    const int nw24 = (D_H * D_H) / 4;
    const int tot4 = nx4 + 2 * nw14 + 2 * nw24;
    const int convblk = (tot4 + 255) / 256;
    hist_conv_k<<<512 + convblk, 256, 0, stream>>>(
        dst, deg, rank, E,
        x, xb, nx4, W1l, w1lb, W1r, w1rb, nw14, W2l, w2lb, W2r, w2rb, nw24);

    // scan + scatter
    const int nseg = (M + 2047) / 2048;     // 25
    scan_part_k<<<nseg, 256, 0, stream>>>(deg, bsum, M);
    scan_final_k<<<nseg, 256, 0, stream>>>(deg, bsum, rp, M, E);
    scatter_k<<<512, 256, 0, stream>>>(src, dst, rank, rp, col, E);

    const int nblk = (M + 127) / 128;
    const int ablk = (M + 3) / 4;

    // layer 1
    aggregate_v3<D_IN><<<ablk, 256, 0, stream>>>(xb, col, rp, mean1, M);
    gemm_mfma_k<D_IN, false><<<nblk, 256, 0, stream>>>(
        mean1, w1lb, xb, w1rb, b1, h1, nullptr, nullptr, nullptr, M);

    // layer 2 + fused head
    aggregate_v3<D_H><<<ablk, 256, 0, stream>>>(h1, col, rp, mean2, M);
    gemm_mfma_k<D_H, true><<<nblk, 256, 0, stream>>>(
        mean2, w2lb, h1, w2rb, b2, nullptr, hw, hb, out, M);
}

// Round 11
// 251.816 us; speedup vs baseline: 1.2058x; 1.2058x over previous
//
#include <hip/hip_runtime.h>
#include <hip/hip_bf16.h>
#include <hip/hip_fp8.h>

#define D_IN 128
#define D_H  256

typedef __attribute__((ext_vector_type(8))) short short8;   // 8 bf16 (4 VGPRs)
typedef __attribute__((ext_vector_type(4))) float floatx4;  // MFMA C/D frag

__device__ __forceinline__ unsigned short f2bf(float f) {
    __hip_bfloat16 h = __float2bfloat16(f);
    return *reinterpret_cast<unsigned short*>(&h);
}
__device__ __forceinline__ float bf2f(unsigned short s) {
    union { unsigned int u; float f; } v;
    v.u = ((unsigned int)s) << 16;
    return v.f;
}

// ------------- fused: histogram (+rank) AND fp32->bf16 conversions ---------
__global__ void hist_conv_k(const int* __restrict__ dst, int* __restrict__ deg,
                            int* __restrict__ rank, int E,
                            const float* __restrict__ x, unsigned short* __restrict__ xb, int nx4,
                            const float* __restrict__ w1l, unsigned short* __restrict__ w1lb,
                            const float* __restrict__ w1r, unsigned short* __restrict__ w1rb, int nw14,
                            const float* __restrict__ w2l, unsigned short* __restrict__ w2lb,
                            const float* __restrict__ w2r, unsigned short* __restrict__ w2rb, int nw24) {
    if (blockIdx.x < 512) {
        for (int e = blockIdx.x * 256 + threadIdx.x; e < E; e += 512 * 256)
            rank[e] = atomicAdd(&deg[dst[e]], 1);
        return;
    }
    int i = (blockIdx.x - 512) * 256 + threadIdx.x;
    const float* s; unsigned short* d; int k;
    if (i < nx4) { s = x; d = xb; k = i; }
    else {
        i -= nx4;
        if (i < nw14) { s = w1l; d = w1lb; k = i; }
        else {
            i -= nw14;
            if (i < nw14) { s = w1r; d = w1rb; k = i; }
            else {
                i -= nw14;
                if (i < nw24) { s = w2l; d = w2lb; k = i; }
                else {
                    i -= nw24;
                    if (i >= nw24) return;
                    s = w2r; d = w2rb; k = i;
                }
            }
        }
    }
    float4 v = ((const float4*)s)[k];
    ushort4 u;
    u.x = f2bf(v.x); u.y = f2bf(v.y); u.z = f2bf(v.z); u.w = f2bf(v.w);
    ((ushort4*)d)[k] = u;
}

__global__ __launch_bounds__(256) void scan_part_k(const int* __restrict__ deg,
                                                   int* __restrict__ bsum, int n) {
    const int b = blockIdx.x, tid = threadIdx.x;
    const int base = b * 2048;
    const int lim = min(base + 2048, n);
    int s = 0;
    for (int i = base + tid; i < lim; i += 256) s += deg[i];
    __shared__ int red[256];
    red[tid] = s; __syncthreads();
    for (int off = 128; off > 0; off >>= 1) {
        if (tid < off) red[tid] += red[tid + off];
        __syncthreads();
    }
    if (tid == 0) bsum[b] = red[0];
}

__global__ __launch_bounds__(256) void scan_final_k(const int* __restrict__ deg,
                                                    const int* __restrict__ bsum,
                                                    int* __restrict__ row_ptr,
                                                    int n, int E) {
    const int b = blockIdx.x, tid = threadIdx.x;
    const int base = b * 2048;
    __shared__ int buf[2048];
    __shared__ int ts[256];
    __shared__ int blk_prefix;
    if (tid == 0) {
        int p = 0;
        for (int i = 0; i < b; ++i) p += bsum[i];
        blk_prefix = p;
    }
    for (int i = tid; i < 2048; i += 256)
        buf[i] = (base + i < n) ? deg[base + i] : 0;
    __syncthreads();
    int local[8];
    int s = 0;
#pragma unroll
    for (int j = 0; j < 8; ++j) { local[j] = s; s += buf[tid * 8 + j]; }
    ts[tid] = s; __syncthreads();
    for (int off = 1; off < 256; off <<= 1) {
        int v = (tid >= off) ? ts[tid - off] : 0;
        __syncthreads();
        ts[tid] += v;
        __syncthreads();
    }
    const int prefix = blk_prefix + ((tid == 0) ? 0 : ts[tid - 1]);
#pragma unroll
    for (int j = 0; j < 8; ++j) {
        int idx = base + tid * 8 + j;
        if (idx < n) row_ptr[idx] = prefix + local[j];
    }
    if (b == 0 && tid == 0) row_ptr[n] = E;
}

__global__ void scatter_k(const int* __restrict__ src, const int* __restrict__ dst,
                          const int* __restrict__ rank, const int* __restrict__ row_ptr,
                          int* __restrict__ col, int E) {
    for (int e = blockIdx.x * blockDim.x + threadIdx.x; e < E; e += gridDim.x * blockDim.x)
        col[row_ptr[dst[e]] + rank[e]] = src[e];
}

// ---------------- mean aggregation v3 (bf16 source, R7-proven) ----------
template <int D, int UN>
__device__ __forceinline__ int agg_stage(const unsigned short* __restrict__ X,
                                         const int* __restrict__ col,
                                         int j, int e, int lane, float* acc) {
    constexpr int V = D / 64;
    for (; j + UN <= e; j += UN) {
        int cs[UN];
#pragma unroll
        for (int u = 0; u < UN; ++u) cs[u] = col[j + u];
        if constexpr (V == 2) {
            unsigned int vals[UN];
#pragma unroll
            for (int u = 0; u < UN; ++u)
                vals[u] = *(const unsigned int*)(X + (size_t)cs[u] * D + lane * 2);
#pragma unroll
            for (int u = 0; u < UN; ++u) {
                acc[0] += bf2f((unsigned short)(vals[u] & 0xffff));
                acc[1] += bf2f((unsigned short)(vals[u] >> 16));
            }
        } else {
            ushort4 vals[UN];
#pragma unroll
            for (int u = 0; u < UN; ++u)
                vals[u] = *(const ushort4*)(X + (size_t)cs[u] * D + lane * 4);
#pragma unroll
            for (int u = 0; u < UN; ++u) {
                acc[0] += bf2f(vals[u].x); acc[1] += bf2f(vals[u].y);
                acc[2] += bf2f(vals[u].z); acc[3] += bf2f(vals[u].w);
            }
        }
    }
    return j;
}

template <int D>
__global__ __launch_bounds__(256) void aggregate_v3(
    const unsigned short* __restrict__ X, const int* __restrict__ col,
    const int* __restrict__ rp, unsigned short* __restrict__ out, int Mnodes) {
    int node = __builtin_amdgcn_readfirstlane((blockIdx.x << 2) + (threadIdx.x >> 6));
    if (node >= Mnodes) return;
    const int lane = threadIdx.x & 63;
    const int s = rp[node], e = rp[node + 1];
    constexpr int V = D / 64;
    float acc[V] = {0.f};

    int j = s;
    j = agg_stage<D, 8>(X, col, j, e, lane, acc);
    j = agg_stage<D, 4>(X, col, j, e, lane, acc);
    j = agg_stage<D, 2>(X, col, j, e, lane, acc);
    j = agg_stage<D, 1>(X, col, j, e, lane, acc);

    const float inv = 1.f / fmaxf((float)(e - s), 1.f);
    if constexpr (V == 2) {
        ushort2 o;
        o.x = f2bf(acc[0] * inv); o.y = f2bf(acc[1] * inv);
        *(ushort2*)(out + (size_t)node * D + lane * 2) = o;
    } else {
        ushort4 o;
        o.x = f2bf(acc[0] * inv); o.y = f2bf(acc[1] * inv);
        o.z = f2bf(acc[2] * inv); o.w = f2bf(acc[3] * inv);
        *(ushort4*)(out + (size_t)node * D + lane * 4) = o;
    }
}

// ---------------- mean aggregation, fp8 source (d=256) ----------
// lane loads 4 fp8 bytes (uint) of a row; fp8x4 -> float4 HW convert.
template <int UN>
__device__ __forceinline__ int agg_stage_fp8(const unsigned char* __restrict__ X8,
                                             const int* __restrict__ col,
                                             int j, int e, int lane, float* acc) {
    for (; j + UN <= e; j += UN) {
        int cs[UN];
#pragma unroll
        for (int u = 0; u < UN; ++u) cs[u] = col[j + u];
        unsigned int vals[UN];
#pragma unroll
        for (int u = 0; u < UN; ++u)
            vals[u] = *(const unsigned int*)(X8 + (size_t)cs[u] * 256 + lane * 4);
#pragma unroll
        for (int u = 0; u < UN; ++u) {
            __hip_fp8x4_e4m3 p;
            p.__x = vals[u];
            float4 f = (float4)p;
            acc[0] += f.x; acc[1] += f.y; acc[2] += f.z; acc[3] += f.w;
        }
    }
    return j;
}

__global__ __launch_bounds__(256) void aggregate_fp8_k(
    const unsigned char* __restrict__ X8, const int* __restrict__ col,
    const int* __restrict__ rp, unsigned short* __restrict__ out, int Mnodes) {
    int node = __builtin_amdgcn_readfirstlane((blockIdx.x << 2) + (threadIdx.x >> 6));
    if (node >= Mnodes) return;
    const int lane = threadIdx.x & 63;
    const int s = rp[node], e = rp[node + 1];
    float acc[4] = {0.f, 0.f, 0.f, 0.f};

    int j = s;
    j = agg_stage_fp8<8>(X8, col, j, e, lane, acc);
    j = agg_stage_fp8<4>(X8, col, j, e, lane, acc);
    j = agg_stage_fp8<2>(X8, col, j, e, lane, acc);
    j = agg_stage_fp8<1>(X8, col, j, e, lane, acc);

    const float inv = 1.f / fmaxf((float)(e - s), 1.f);
    ushort4 o;
    o.x = f2bf(acc[0] * inv); o.y = f2bf(acc[1] * inv);
    o.z = f2bf(acc[2] * inv); o.w = f2bf(acc[3] * inv);
    *(ushort4*)(out + (size_t)node * 256 + lane * 4) = o;
}

// ---------------- dual-input bf16 MFMA GEMM, block tile 128 x 256 ----------
// R7-proven VGPR-staging structure. HEAD=false additionally stores Hout8 (fp8)
// as the gather source for the next layer's aggregation.
template <int K, bool HEAD>
__global__ __launch_bounds__(256, 2) void gemm_mfma_k(
    const unsigned short* __restrict__ A1, const unsigned short* __restrict__ W1,
    const unsigned short* __restrict__ A2, const unsigned short* __restrict__ W2,
    const float* __restrict__ bias, unsigned short* __restrict__ Hout,
    unsigned char* __restrict__ Hout8,
    const float* __restrict__ hw, const float* __restrict__ hb,
    float* __restrict__ out, int M) {
    __shared__ __align__(16) unsigned short sA[128 * 40];
    __shared__ __align__(16) unsigned short sB[256 * 40];
    __shared__ float head_acc[128];

    const int tid = threadIdx.x;
    const int wave = tid >> 6;
    const int lane = tid & 63;
    const int c = lane & 15;
    const int q = lane >> 4;
    const int m0 = blockIdx.x * 128;

    if (HEAD && tid < 128) head_acc[tid] = 0.f;  // ordered by first k-loop barrier

    floatx4 acc[8][4];
#pragma unroll
    for (int mi = 0; mi < 8; ++mi)
#pragma unroll
        for (int ni = 0; ni < 4; ++ni) acc[mi][ni] = (floatx4){0.f, 0.f, 0.f, 0.f};

    const int arow = tid >> 1;          // 0..127
    const int aseg = (tid & 1) * 16;    // 0 or 16 (ushorts)
    const int brow = tid >> 2;          // 0..63
    const int bseg = (tid & 3) * 8;
    int gr = m0 + arow;
    if (gr >= M) gr = M - 1;            // clamp; stores guarded

    for (int phase = 0; phase < 2; ++phase) {
        const unsigned short* Ap = phase ? A2 : A1;
        const unsigned short* Wp = phase ? W2 : W1;
        for (int k0 = 0; k0 < K; k0 += 32) {
            short8 va0 = *(const short8*)(Ap + (size_t)gr * K + k0 + aseg);
            short8 va1 = *(const short8*)(Ap + (size_t)gr * K + k0 + aseg + 8);
            short8 vb[4];
#pragma unroll
            for (int i = 0; i < 4; ++i)
                vb[i] = *(const short8*)(Wp + (size_t)(brow + i * 64) * K + k0 + bseg);
            __syncthreads();
            *(short8*)&sA[arow * 40 + aseg] = va0;
            *(short8*)&sA[arow * 40 + aseg + 8] = va1;
#pragma unroll
            for (int i = 0; i < 4; ++i)
                *(short8*)&sB[(brow + i * 64) * 40 + bseg] = vb[i];
            __syncthreads();

            short8 af[8], bf[4];
#pragma unroll
            for (int mi = 0; mi < 8; ++mi)
                af[mi] = *(const short8*)&sA[(mi * 16 + c) * 40 + q * 8];
#pragma unroll
            for (int ni = 0; ni < 4; ++ni)
                bf[ni] = *(const short8*)&sB[(wave * 64 + ni * 16 + c) * 40 + q * 8];
#pragma unroll
            for (int mi = 0; mi < 8; ++mi)
#pragma unroll
                for (int ni = 0; ni < 4; ++ni)
                    acc[mi][ni] = __builtin_amdgcn_mfma_f32_16x16x32_bf16(
                        af[mi], bf[ni], acc[mi][ni], 0, 0, 0);
        }
    }

    if (!HEAD) {
#pragma unroll
        for (int mi = 0; mi < 8; ++mi)
#pragma unroll
            for (int ni = 0; ni < 4; ++ni) {
                const int n = wave * 64 + ni * 16 + c;
                const float bv = bias[n];
#pragma unroll
                for (int reg = 0; reg < 4; ++reg) {
                    const int m = m0 + mi * 16 + q * 4 + reg;
                    if (m < M) {
                        float v = fmaxf(acc[mi][ni][reg] + bv, 0.f);
                        Hout[(size_t)m * 256 + n] = f2bf(v);
                        __hip_fp8_e4m3 t(v);
                        Hout8[(size_t)m * 256 + n] = (unsigned char)t.__x;
                    }
                }
            }
    } else {
#pragma unroll
        for (int mi = 0; mi < 8; ++mi) {
            float p[4] = {0.f, 0.f, 0.f, 0.f};
#pragma unroll
            for (int ni = 0; ni < 4; ++ni) {
                const int n = wave * 64 + ni * 16 + c;
                const float bv = bias[n];
                const float hv = hw[n];
#pragma unroll
                for (int reg = 0; reg < 4; ++reg)
                    p[reg] += fmaxf(acc[mi][ni][reg] + bv, 0.f) * hv;
            }
#pragma unroll
            for (int reg = 0; reg < 4; ++reg) {
                float v = p[reg];
                v += __shfl_xor(v, 1, 64);
                v += __shfl_xor(v, 2, 64);
                v += __shfl_xor(v, 4, 64);
                v += __shfl_xor(v, 8, 64);
                if (c == 0) atomicAdd(&head_acc[mi * 16 + q * 4 + reg], v);
            }
        }
        __syncthreads();
        if (tid < 128) {
            const int m = m0 + tid;
            if (m < M) out[m] = head_acc[tid] + hb[0];
        }
    }
}

// ---------------- launch ----------------
extern "C" void kernel_launch(void* const* d_in, const int* in_sizes, int n_in,
                              void* d_out, int out_size, void* d_ws, size_t ws_size,
                              hipStream_t stream) {
    const float* x    = (const float*)d_in[0];
    const int*   ei   = (const int*)d_in[1];
    const float* W1l  = (const float*)d_in[2];
    const float* b1   = (const float*)d_in[3];
    const float* W1r  = (const float*)d_in[4];
    const float* W2l  = (const float*)d_in[5];
    const float* b2   = (const float*)d_in[6];
    const float* W2r  = (const float*)d_in[7];
    const float* hw   = (const float*)d_in[8];
    const float* hb   = (const float*)d_in[9];
    float* out = (float*)d_out;

    const int M = in_sizes[0] / D_IN;       // 50000
    const int E = in_sizes[1] / 2;          // 800000
    const int* src = ei;
    const int* dst = ei + E;

    size_t off = 0;
    auto alloc = [&](size_t bytes) -> void* {
        void* p = (char*)d_ws + off;
        off += (bytes + 255) & ~(size_t)255;
        return p;
    };
    int* deg  = (int*)alloc((size_t)M * 4);
    int* rp   = (int*)alloc((size_t)(M + 1) * 4);
    int* bsum = (int*)alloc(256 * 4);
    int* rank = (int*)alloc((size_t)E * 4);
    int* col  = (int*)alloc((size_t)E * 4);
    unsigned short* xb    = (unsigned short*)alloc((size_t)M * D_IN * 2);
    unsigned short* w1lb  = (unsigned short*)alloc((size_t)D_H * D_IN * 2);
    unsigned short* w1rb  = (unsigned short*)alloc((size_t)D_H * D_IN * 2);
    unsigned short* w2lb  = (unsigned short*)alloc((size_t)D_H * D_H * 2);
    unsigned short* w2rb  = (unsigned short*)alloc((size_t)D_H * D_H * 2);
    unsigned short* mean1 = (unsigned short*)alloc((size_t)M * D_IN * 2);
    unsigned short* h1    = (unsigned short*)alloc((size_t)M * D_H * 2);
    unsigned char*  h8    = (unsigned char*)alloc((size_t)M * D_H);
    unsigned short* mean2 = (unsigned short*)alloc((size_t)M * D_H * 2);

    hipMemsetAsync(deg, 0, (size_t)M * 4, stream);

    // fused histogram + conversions
    const int nx4 = (M * D_IN) / 4;
    const int nw14 = (D_H * D_IN) / 4;
    const int nw24 = (D_H * D_H) / 4;
    const int tot4 = nx4 + 2 * nw14 + 2 * nw24;
    const int convblk = (tot4 + 255) / 256;
    hist_conv_k<<<512 + convblk, 256, 0, stream>>>(
        dst, deg, rank, E,
        x, xb, nx4, W1l, w1lb, W1r, w1rb, nw14, W2l, w2lb, W2r, w2rb, nw24);

    // scan + scatter
    const int nseg = (M + 2047) / 2048;     // 25
    scan_part_k<<<nseg, 256, 0, stream>>>(deg, bsum, M);
    scan_final_k<<<nseg, 256, 0, stream>>>(deg, bsum, rp, M, E);
    scatter_k<<<512, 256, 0, stream>>>(src, dst, rank, rp, col, E);

    const int nblk = (M + 127) / 128;
    const int ablk = (M + 3) / 4;

    // layer 1
    aggregate_v3<D_IN><<<ablk, 256, 0, stream>>>(xb, col, rp, mean1, M);
    gemm_mfma_k<D_IN, false><<<nblk, 256, 0, stream>>>(
        mean1, w1lb, xb, w1rb, b1, h1, h8, nullptr, nullptr, nullptr, M);

    // layer 2 + fused head (gather from fp8 h8; self path stays bf16 h1)
    aggregate_fp8_k<<<ablk, 256, 0, stream>>>(h8, col, rp, mean2, M);
    gemm_mfma_k<D_H, true><<<nblk, 256, 0, stream>>>(
        mean2, w2lb, h1, w2rb, b2, nullptr, nullptr, hw, hb, out, M);
}